// Round 1
// baseline (369.593 us; speedup 1.0000x reference)
//
#include <hip/hip_runtime.h>
#include <hip/hip_bf16.h>

// SplitMLP: B=128, C=16, V=32, H=64, O=4, G=10000
// One block (256 thr / 4 waves) per group g.
// fc1: A=[day|items_g|pad0] (128x64bf16) @ W1^T (64x64) via mfma_f32_16x16x32_bf16
// fc2: relu(h) (128x64) @ W2^T (64x4, N-padded to 16) via same MFMA.
// All accumulation fp32; inputs rounded to bf16 (error ~4e-7 << 2.78e-5 threshold).

typedef __bf16 v8bf __attribute__((ext_vector_type(8)));
typedef __bf16 v4bf __attribute__((ext_vector_type(4)));
typedef float  v4f  __attribute__((ext_vector_type(4)));

#define B_  128
#define C_  16
#define V_  32
#define H_  64
#define O_  4
#define G_  10000
#define AK  72   // padded K stride (bf16 elems), 144 B: 16B-aligned rows, 2-way-max banks

__device__ __forceinline__ v4bf cvt4(float4 f) {
  v4bf r;
  r[0] = (__bf16)f.x; r[1] = (__bf16)f.y; r[2] = (__bf16)f.z; r[3] = (__bf16)f.w;
  return r;
}

__global__ __launch_bounds__(256, 3)
void splitmlp_kernel(const float* __restrict__ day,
                     const float* __restrict__ items,
                     const float* __restrict__ W1d,
                     const float* __restrict__ W1v,
                     const float* __restrict__ b1,
                     const float* __restrict__ W2,
                     const float* __restrict__ b2,
                     float* __restrict__ out) {
  __shared__ alignas(16) __bf16 Abuf[B_ * AK];   // [b][k] k: 0..15 day, 16..47 items, 48..63 zero
  __shared__ alignas(16) __bf16 Wbuf[H_ * AK];   // [h][k] same k layout
  __shared__ alignas(16) __bf16 Hbuf[B_ * AK];   // [b][h] relu(fc1) as bf16
  __shared__ alignas(16) __bf16 W2buf[16 * H_];  // [o][h], rows 4..15 zero
  __shared__ float b1s[H_];
  __shared__ float b2s[O_];

  const int t = threadIdx.x;
  const int g = blockIdx.x;

  __bf16 zb = (__bf16)0.0f;
  v4bf z4 = {zb, zb, zb, zb};

  // ---------------- staging (fp32 -> bf16 -> LDS) ----------------
  // day (128x16) -> Abuf cols 0..15   (512 float4)
  {
    const float4* p = reinterpret_cast<const float4*>(day);
#pragma unroll
    for (int i = t; i < 512; i += 256) {
      int b = i >> 2, c4 = (i & 3) << 2;
      *reinterpret_cast<v4bf*>(&Abuf[b * AK + c4]) = cvt4(p[i]);
    }
  }
  // items (128 rows x 32) -> Abuf cols 16..47   (1024 float4, 128B contiguous per row)
  {
#pragma unroll
    for (int i = t; i < 1024; i += 256) {
      int b = i >> 3, v4i = (i & 7) << 2;
      const float4* p = reinterpret_cast<const float4*>(
          items + (size_t)b * (G_ * V_) + (size_t)g * V_ + v4i);
      *reinterpret_cast<v4bf*>(&Abuf[b * AK + C_ + v4i]) = cvt4(*p);
    }
  }
  // zero Abuf cols 48..63   (512 chunks of 4)
  {
#pragma unroll
    for (int i = t; i < 512; i += 256) {
      int b = i >> 2, c4 = 48 + ((i & 3) << 2);
      *reinterpret_cast<v4bf*>(&Abuf[b * AK + c4]) = z4;
    }
  }
  // W1_day (64x16) -> Wbuf cols 0..15   (256 float4)
  {
    const float4* p = reinterpret_cast<const float4*>(W1d + (size_t)g * (H_ * C_));
    int h = t >> 2, c4 = (t & 3) << 2;
    *reinterpret_cast<v4bf*>(&Wbuf[h * AK + c4]) = cvt4(p[t]);
  }
  // W1_var (64x32) -> Wbuf cols 16..47   (512 float4)
  {
    const float4* p = reinterpret_cast<const float4*>(W1v + (size_t)g * (H_ * V_));
#pragma unroll
    for (int i = t; i < 512; i += 256) {
      int h = i >> 3, v4i = (i & 7) << 2;
      *reinterpret_cast<v4bf*>(&Wbuf[h * AK + C_ + v4i]) = cvt4(p[i]);
    }
  }
  // zero Wbuf cols 48..63   (256 chunks)
  {
    int h = t >> 2, c4 = 48 + ((t & 3) << 2);
    *reinterpret_cast<v4bf*>(&Wbuf[h * AK + c4]) = z4;
  }
  // W2 (4x64) -> W2buf rows 0..3; zero rows 4..15
  if (t < 64) {
    const float4* p = reinterpret_cast<const float4*>(W2 + (size_t)g * (O_ * H_));
    int o = t >> 4, h4 = (t & 15) << 2;
    *reinterpret_cast<v4bf*>(&W2buf[o * H_ + h4]) = cvt4(p[t]);
  }
  if (t < 192) {
    int o = 4 + (t >> 4), h4 = (t & 15) << 2;
    *reinterpret_cast<v4bf*>(&W2buf[o * H_ + h4]) = z4;
  }
  if (t < H_) b1s[t] = b1[(size_t)g * H_ + t];
  if (t < O_) b2s[t] = b2[(size_t)g * O_ + t];

  __syncthreads();

  // ---------------- fc1: 128x64 = A(128x64) @ W1^T ----------------
  const int w = t >> 6;        // wave 0..3 -> rows [32w, 32w+32)
  const int lane = t & 63;
  const int c = lane & 15;     // col within 16-tile (n for B/D, m for A)
  const int q = lane >> 4;     // quad -> k-block / row-block
  const int rowA0 = w * 32 + c;
  const int rowA1 = rowA0 + 16;

  v4f zero = {0.f, 0.f, 0.f, 0.f};
  v4f acc[2][4];
#pragma unroll
  for (int m = 0; m < 2; ++m)
#pragma unroll
    for (int n = 0; n < 4; ++n) acc[m][n] = zero;

#pragma unroll
  for (int kt = 0; kt < 2; ++kt) {
    int k0 = kt * 32 + q * 8;
    v8bf a0 = *reinterpret_cast<const v8bf*>(&Abuf[rowA0 * AK + k0]);
    v8bf a1 = *reinterpret_cast<const v8bf*>(&Abuf[rowA1 * AK + k0]);
#pragma unroll
    for (int n = 0; n < 4; ++n) {
      v8bf bw = *reinterpret_cast<const v8bf*>(&Wbuf[(n * 16 + c) * AK + k0]);
      acc[0][n] = __builtin_amdgcn_mfma_f32_16x16x32_bf16(a0, bw, acc[0][n], 0, 0, 0);
      acc[1][n] = __builtin_amdgcn_mfma_f32_16x16x32_bf16(a1, bw, acc[1][n], 0, 0, 0);
    }
  }

  // epilogue: + b1, ReLU, -> Hbuf bf16. C/D layout: col=lane&15, row=quad*4+reg.
  // Wave w writes exactly rows [32w,32w+32) -> fc2 reads are wave-local, no barrier.
#pragma unroll
  for (int n = 0; n < 4; ++n) {
    float bias = b1s[n * 16 + c];
#pragma unroll
    for (int m = 0; m < 2; ++m) {
      int rb = w * 32 + m * 16 + q * 4;
#pragma unroll
      for (int r = 0; r < 4; ++r) {
        float v = acc[m][n][r] + bias;
        v = fmaxf(v, 0.0f);
        Hbuf[(rb + r) * AK + n * 16 + c] = (__bf16)v;
      }
    }
  }

  // ---------------- fc2: y(128x4) = relu(h) @ W2^T (N padded to 16) ----------------
  v4f y0 = zero, y1 = zero;
#pragma unroll
  for (int kt = 0; kt < 2; ++kt) {
    int k0 = kt * 32 + q * 8;
    v8bf h0  = *reinterpret_cast<const v8bf*>(&Hbuf[rowA0 * AK + k0]);
    v8bf h1  = *reinterpret_cast<const v8bf*>(&Hbuf[rowA1 * AK + k0]);
    v8bf w2f = *reinterpret_cast<const v8bf*>(&W2buf[c * H_ + k0]);
    y0 = __builtin_amdgcn_mfma_f32_16x16x32_bf16(h0, w2f, y0, 0, 0, 0);
    y1 = __builtin_amdgcn_mfma_f32_16x16x32_bf16(h1, w2f, y1, 0, 0, 0);
  }

  // store: lanes with col<4 hold y[b][o]; out[b*G*O + g*O + o]
  if (c < O_) {
    float bb = b2s[c];
#pragma unroll
    for (int m = 0; m < 2; ++m) {
      int rb = w * 32 + m * 16 + q * 4;
      v4f ym = (m == 0) ? y0 : y1;
#pragma unroll
      for (int r = 0; r < 4; ++r) {
        out[(size_t)(rb + r) * (G_ * O_) + (size_t)g * O_ + c] = ym[r] + bb;
      }
    }
  }
}

extern "C" void kernel_launch(void* const* d_in, const int* in_sizes, int n_in,
                              void* d_out, int out_size, void* d_ws, size_t ws_size,
                              hipStream_t stream) {
  const float* day   = (const float*)d_in[0];
  const float* items = (const float*)d_in[1];
  const float* W1d   = (const float*)d_in[2];
  const float* W1v   = (const float*)d_in[3];
  const float* b1    = (const float*)d_in[4];
  const float* W2    = (const float*)d_in[5];
  const float* b2    = (const float*)d_in[6];
  float* out = (float*)d_out;
  splitmlp_kernel<<<G_, 256, 0, stream>>>(day, items, W1d, W1v, b1, W2, b2, out);
}